// Round 3
// baseline (1421.562 us; speedup 1.0000x reference)
//
#include <hip/hip_runtime.h>

#define F 128
#define BN 64

// ---------------- CSR build ----------------

__global__ __launch_bounds__(256) void count_kernel(const int* __restrict__ dst,
                                                    int* __restrict__ cnt, int e) {
    int i = blockIdx.x * 256 + threadIdx.x;
    if (i < e) atomicAdd(&cnt[dst[i]], 1);
}

__global__ __launch_bounds__(256) void dinv_kernel(const int* __restrict__ cnt,
                                                   float* __restrict__ dinv, int n) {
    int i = blockIdx.x * 256 + threadIdx.x;
    if (i < n) dinv[i] = rsqrtf((float)(cnt[i] + 1));  // +1 self loop
}

__global__ __launch_bounds__(1024) void scan_kernel(const int* __restrict__ cnt,
                                                    int* __restrict__ offs, int n) {
    __shared__ int sm[1024];
    int tid = threadIdx.x;
    int chunk = (n + 1023) >> 10;
    int b = tid * chunk;
    int e = b + chunk; if (e > n) e = n;
    int s = 0;
    for (int i = b; i < e; i++) s += cnt[i];
    sm[tid] = s;
    __syncthreads();
    for (int d = 1; d < 1024; d <<= 1) {
        int v = 0;
        if (tid >= d) v = sm[tid - d];
        __syncthreads();
        if (tid >= d) sm[tid] += v;
        __syncthreads();
    }
    int run = (tid == 0) ? 0 : sm[tid - 1];
    for (int i = b; i < e; i++) { offs[i] = run; run += cnt[i]; }
    if (tid == 1023) offs[n] = sm[1023];
}

__global__ __launch_bounds__(256) void fill_kernel(const int* __restrict__ src,
                                                   const int* __restrict__ dst,
                                                   const int* __restrict__ offs,
                                                   int* __restrict__ cursor,
                                                   const float* __restrict__ dinv,
                                                   int2* __restrict__ csr, int e) {
    int i = blockIdx.x * 256 + threadIdx.x;
    if (i >= e) return;
    int s = src[i], d = dst[i];
    int pos = atomicAdd(&cursor[d], 1);
    int2 pk;
    pk.x = s;
    pk.y = __float_as_int(dinv[s] * dinv[d]);
    csr[offs[d] + pos] = pk;
}

// ---------------- GEMM: out[n][128] = h[n][128] @ W[128][128] ----------------

__global__ __launch_bounds__(256) void gemm_kernel(const float* __restrict__ h,
                                                   const float* __restrict__ W,
                                                   float* __restrict__ out, int n) {
    __shared__ float Ws[128 * 64];   // Ws[k][fh]
    __shared__ float Hs[BN * 128];   // Hs[nn][k ^ ((nn&7)<<2)]  (bank swizzle)
    const int tid = threadIdx.x;
    const int half = blockIdx.y;

    for (int i = tid; i < 128 * 64; i += 256) {
        int k = i >> 6, fh = i & 63;
        Ws[i] = W[k * F + (half << 6) + fh];
    }

    const int fg = tid & 15;
    const int ng = tid >> 4;
    const int f0 = fg << 2;
    const int n0 = ng << 2;
    const int nchunk = (n + BN - 1) / BN;

    for (int c = blockIdx.x; c < nchunk; c += gridDim.x) {
        const int base = c * BN;
        __syncthreads();
        for (int i = tid; i < BN * 128; i += 256) {
            int nn = i >> 7, k = i & 127;
            int node = base + nn;
            float v = (node < n) ? h[(size_t)node * F + k] : 0.0f;
            Hs[(nn << 7) + (k ^ ((nn & 7) << 2))] = v;
        }
        __syncthreads();

        float acc[4][4];
        #pragma unroll
        for (int a = 0; a < 4; a++)
            #pragma unroll
            for (int b = 0; b < 4; b++) acc[a][b] = 0.0f;

        #pragma unroll 2
        for (int kk = 0; kk < 128; kk += 4) {
            float4 w0 = *(const float4*)&Ws[((kk + 0) << 6) + f0];
            float4 w1 = *(const float4*)&Ws[((kk + 1) << 6) + f0];
            float4 w2 = *(const float4*)&Ws[((kk + 2) << 6) + f0];
            float4 w3 = *(const float4*)&Ws[((kk + 3) << 6) + f0];
            #pragma unroll
            for (int j = 0; j < 4; j++) {
                const int nn = n0 + j;
                float4 hv = *(const float4*)&Hs[(nn << 7) + (kk ^ ((nn & 7) << 2))];
                acc[j][0] += hv.x * w0.x + hv.y * w1.x + hv.z * w2.x + hv.w * w3.x;
                acc[j][1] += hv.x * w0.y + hv.y * w1.y + hv.z * w2.y + hv.w * w3.y;
                acc[j][2] += hv.x * w0.z + hv.y * w1.z + hv.z * w2.z + hv.w * w3.z;
                acc[j][3] += hv.x * w0.w + hv.y * w1.w + hv.z * w2.w + hv.w * w3.w;
            }
        }

        #pragma unroll
        for (int j = 0; j < 4; j++) {
            int node = base + n0 + j;
            if (node < n) {
                float4 v = make_float4(acc[j][0], acc[j][1], acc[j][2], acc[j][3]);
                *(float4*)&out[(size_t)node * F + (half << 6) + f0] = v;
            }
        }
    }
}

// ---------------- Aggregate: block-per-node, 4 waves split edges, float2/lane ----

template <int POOL>
__global__ __launch_bounds__(256) void agg_kernel(const float* __restrict__ hl,
                                                  const int* __restrict__ offs,
                                                  const int2* __restrict__ csr,
                                                  const float* __restrict__ dinv,
                                                  const float* __restrict__ bias,
                                                  float* __restrict__ out,
                                                  const int* __restrict__ batch, int n) {
    const int i = blockIdx.x;                 // node
    const int lane = threadIdx.x & 63;
    const int w = threadIdx.x >> 6;           // wave 0..3
    __shared__ float2 part[3][64];

    const float2* __restrict__ hl2 = (const float2*)hl;

    float ax = 0.0f, ay = 0.0f;
    const int e0 = offs[i], e1 = offs[i + 1];

    // wave w processes edges e0+w, e0+w+4, ... ; unroll 2 -> 2 rows in flight
    int e = e0 + w;
    for (; e + 4 < e1; e += 8) {
        int2 p0 = csr[e];
        int2 p1 = csr[e + 4];
        float2 r0 = hl2[(size_t)p0.x * 64 + lane];
        float2 r1 = hl2[(size_t)p1.x * 64 + lane];
        float f0v = __int_as_float(p0.y), f1v = __int_as_float(p1.y);
        ax += r0.x * f0v + r1.x * f1v;
        ay += r0.y * f0v + r1.y * f1v;
    }
    if (e < e1) {
        int2 pk = csr[e];
        float2 r = hl2[(size_t)pk.x * 64 + lane];
        float nf = __int_as_float(pk.y);
        ax += r.x * nf;
        ay += r.y * nf;
    }

    if (w == 0) {                              // self loop on wave 0
        float di = dinv[i];
        float2 s = hl2[(size_t)i * 64 + lane];
        ax += s.x * di * di;
        ay += s.y * di * di;
    } else {
        part[w - 1][lane] = make_float2(ax, ay);
    }
    __syncthreads();
    if (w == 0) {
        #pragma unroll
        for (int p = 0; p < 3; p++) {
            ax += part[p][lane].x;
            ay += part[p][lane].y;
        }
        float2 bv = ((const float2*)bias)[lane];
        float rx = fmaxf(ax + bv.x, 0.0f);
        float ry = fmaxf(ay + bv.y, 0.0f);
        if (POOL) {
            int g = batch[i];
            atomicMax((int*)&out[(size_t)g * F + 2 * lane + 0], __float_as_int(rx));
            atomicMax((int*)&out[(size_t)g * F + 2 * lane + 1], __float_as_int(ry));
        } else {
            ((float2*)out)[(size_t)i * 64 + lane] = make_float2(rx, ry);
        }
    }
}

// ---------------- MLP head + log_softmax ----------------

__global__ __launch_bounds__(128) void mlp_kernel(const float* __restrict__ pooled,
                                                  const float* __restrict__ Wp1,
                                                  const float* __restrict__ bp1,
                                                  const float* __restrict__ Wp2,
                                                  const float* __restrict__ bp2,
                                                  float* __restrict__ out) {
    __shared__ float pl[F];
    __shared__ float s0[2], s1[2];
    int g = blockIdx.x, t = threadIdx.x;
    pl[t] = pooled[(size_t)g * F + t];
    __syncthreads();
    float a = bp1[t];
    #pragma unroll 8
    for (int k = 0; k < F; k++) a += pl[k] * Wp1[k * F + t];
    float p0 = a * Wp2[t * 2 + 0];
    float p1 = a * Wp2[t * 2 + 1];
    #pragma unroll
    for (int d = 32; d > 0; d >>= 1) {
        p0 += __shfl_down(p0, d, 64);
        p1 += __shfl_down(p1, d, 64);
    }
    if ((t & 63) == 0) { s0[t >> 6] = p0; s1[t >> 6] = p1; }
    __syncthreads();
    if (t == 0) {
        float l0 = s0[0] + s0[1] + bp2[0];
        float l1 = s1[0] + s1[1] + bp2[1];
        float m = fmaxf(l0, l1);
        float lse = m + logf(expf(l0 - m) + expf(l1 - m));
        out[g * 2 + 0] = l0 - lse;
        out[g * 2 + 1] = l1 - lse;
    }
}

// ---------------- launch ----------------

extern "C" void kernel_launch(void* const* d_in, const int* in_sizes, int n_in,
                              void* d_out, int out_size, void* d_ws, size_t ws_size,
                              hipStream_t stream) {
    const float* x    = (const float*)d_in[0];
    const int*   ei   = (const int*)d_in[1];
    const int*   batch= (const int*)d_in[2];
    const float* W1 = (const float*)d_in[3];  const float* b1 = (const float*)d_in[4];
    const float* W2 = (const float*)d_in[5];  const float* b2 = (const float*)d_in[6];
    const float* W3 = (const float*)d_in[7];  const float* b3 = (const float*)d_in[8];
    const float* Wp1= (const float*)d_in[9];  const float* bp1= (const float*)d_in[10];
    const float* Wp2= (const float*)d_in[11]; const float* bp2= (const float*)d_in[12];

    const int N = in_sizes[0] / F;
    const int E = in_sizes[1] / 2;
    const int G = out_size / 2;

    char* w = (char*)d_ws;
    size_t off = 0;
    auto alloc = [&](size_t bytes) -> void* {
        void* p = w + off;
        off = (off + bytes + 255) & ~(size_t)255;
        return p;
    };
    float* bufA   = (float*)alloc((size_t)N * F * 4);
    float* bufB   = (float*)alloc((size_t)N * F * 4);
    int*   deg    = (int*)alloc((size_t)N * 4);
    int*   cursor = (int*)alloc((size_t)N * 4);
    int*   offs   = (int*)alloc((size_t)(N + 1) * 4);
    float* dinv   = (float*)alloc((size_t)N * 4);
    int2*  csr    = (int2*)alloc((size_t)E * 8);
    float* pooled = (float*)alloc((size_t)G * F * 4);

    const int* srcp = ei;
    const int* dstp = ei + E;

    hipMemsetAsync(deg,    0, (size_t)N * 4, stream);
    hipMemsetAsync(cursor, 0, (size_t)N * 4, stream);
    hipMemsetAsync(pooled, 0, (size_t)G * F * 4, stream);

    const int eb = (E + 255) / 256;
    const int nb = (N + 255) / 256;
    count_kernel<<<eb, 256, 0, stream>>>(dstp, deg, E);
    dinv_kernel<<<nb, 256, 0, stream>>>(deg, dinv, N);
    scan_kernel<<<1, 1024, 0, stream>>>(deg, offs, N);
    fill_kernel<<<eb, 256, 0, stream>>>(srcp, dstp, offs, cursor, dinv, csr, E);

    dim3 gg(512, 2);
    gemm_kernel<<<gg, 256, 0, stream>>>(x, W1, bufA, N);
    agg_kernel<0><<<N, 256, 0, stream>>>(bufA, offs, csr, dinv, b1, bufB, nullptr, N);
    gemm_kernel<<<gg, 256, 0, stream>>>(bufB, W2, bufA, N);
    agg_kernel<0><<<N, 256, 0, stream>>>(bufA, offs, csr, dinv, b2, bufB, nullptr, N);
    gemm_kernel<<<gg, 256, 0, stream>>>(bufB, W3, bufA, N);
    agg_kernel<1><<<N, 256, 0, stream>>>(bufA, offs, csr, dinv, b3, pooled, batch, N);
    mlp_kernel<<<G, 128, 0, stream>>>(pooled, Wp1, bp1, Wp2, bp2, (float*)d_out);
}

// Round 5
// 1096.951 us; speedup vs baseline: 1.2959x; 1.2959x over previous
//
#include <hip/hip_runtime.h>

#define F 128
#define BN 64

// ---------------- CSR build ----------------

__global__ __launch_bounds__(256) void count_kernel(const int* __restrict__ dst,
                                                    int* __restrict__ cnt, int e) {
    int i = blockIdx.x * 256 + threadIdx.x;
    if (i < e) atomicAdd(&cnt[dst[i]], 1);
}

__global__ __launch_bounds__(256) void dinv_kernel(const int* __restrict__ cnt,
                                                   float* __restrict__ dinv, int n) {
    int i = blockIdx.x * 256 + threadIdx.x;
    if (i < n) dinv[i] = rsqrtf((float)(cnt[i] + 1));  // +1 self loop
}

__global__ __launch_bounds__(1024) void scan_kernel(const int* __restrict__ cnt,
                                                    int* __restrict__ offs, int n) {
    __shared__ int sm[1024];
    int tid = threadIdx.x;
    int chunk = (n + 1023) >> 10;
    int b = tid * chunk;
    int e = b + chunk; if (e > n) e = n;
    int s = 0;
    for (int i = b; i < e; i++) s += cnt[i];
    sm[tid] = s;
    __syncthreads();
    for (int d = 1; d < 1024; d <<= 1) {
        int v = 0;
        if (tid >= d) v = sm[tid - d];
        __syncthreads();
        if (tid >= d) sm[tid] += v;
        __syncthreads();
    }
    int run = (tid == 0) ? 0 : sm[tid - 1];
    for (int i = b; i < e; i++) { offs[i] = run; run += cnt[i]; }
    if (tid == 1023) offs[n] = sm[1023];
}

__global__ __launch_bounds__(256) void fill_kernel(const int* __restrict__ src,
                                                   const int* __restrict__ dst,
                                                   const int* __restrict__ offs,
                                                   int* __restrict__ cursor,
                                                   const float* __restrict__ dinv,
                                                   int2* __restrict__ csr, int e) {
    int i = blockIdx.x * 256 + threadIdx.x;
    if (i >= e) return;
    int s = src[i], d = dst[i];
    int pos = atomicAdd(&cursor[d], 1);
    int2 pk;
    pk.x = s;
    pk.y = __float_as_int(dinv[s] * dinv[d]);
    csr[offs[d] + pos] = pk;
}

// ---------------- bf16 helpers (bit-level, no type dependence) ----------------

__device__ __forceinline__ unsigned short f32_to_bf16_rne(float x) {
    unsigned u = __float_as_uint(x);
    unsigned r = (u + 0x7fffu + ((u >> 16) & 1u)) >> 16;   // round to nearest even
    return (unsigned short)r;
}

__device__ __forceinline__ float2 bf2unpack(unsigned v) {
    return make_float2(__uint_as_float(v << 16), __uint_as_float(v & 0xffff0000u));
}

// ---------------- GEMM: outb[n][128](bf16) = h[n][128](f32) @ W[128][128] ----------------

__global__ __launch_bounds__(256) void gemm_kernel(const float* __restrict__ h,
                                                   const float* __restrict__ W,
                                                   unsigned short* __restrict__ outb, int n) {
    __shared__ float Ws[128 * 64];   // Ws[k][fh]
    __shared__ float Hs[BN * 128];   // Hs[nn][k ^ ((nn&7)<<2)]  (bank swizzle)
    const int tid = threadIdx.x;
    const int half = blockIdx.y;

    for (int i = tid; i < 128 * 64; i += 256) {
        int k = i >> 6, fh = i & 63;
        Ws[i] = W[k * F + (half << 6) + fh];
    }

    const int fg = tid & 15;
    const int ng = tid >> 4;
    const int f0 = fg << 2;
    const int n0 = ng << 2;
    const int nchunk = (n + BN - 1) / BN;

    for (int c = blockIdx.x; c < nchunk; c += gridDim.x) {
        const int base = c * BN;
        __syncthreads();
        for (int i = tid; i < BN * 128; i += 256) {
            int nn = i >> 7, k = i & 127;
            int node = base + nn;
            float v = (node < n) ? h[(size_t)node * F + k] : 0.0f;
            Hs[(nn << 7) + (k ^ ((nn & 7) << 2))] = v;
        }
        __syncthreads();

        float acc[4][4];
        #pragma unroll
        for (int a = 0; a < 4; a++)
            #pragma unroll
            for (int b = 0; b < 4; b++) acc[a][b] = 0.0f;

        #pragma unroll 2
        for (int kk = 0; kk < 128; kk += 4) {
            float4 w0 = *(const float4*)&Ws[((kk + 0) << 6) + f0];
            float4 w1 = *(const float4*)&Ws[((kk + 1) << 6) + f0];
            float4 w2 = *(const float4*)&Ws[((kk + 2) << 6) + f0];
            float4 w3 = *(const float4*)&Ws[((kk + 3) << 6) + f0];
            #pragma unroll
            for (int j = 0; j < 4; j++) {
                const int nn = n0 + j;
                float4 hv = *(const float4*)&Hs[(nn << 7) + (kk ^ ((nn & 7) << 2))];
                acc[j][0] += hv.x * w0.x + hv.y * w1.x + hv.z * w2.x + hv.w * w3.x;
                acc[j][1] += hv.x * w0.y + hv.y * w1.y + hv.z * w2.y + hv.w * w3.y;
                acc[j][2] += hv.x * w0.z + hv.y * w1.z + hv.z * w2.z + hv.w * w3.z;
                acc[j][3] += hv.x * w0.w + hv.y * w1.w + hv.z * w2.w + hv.w * w3.w;
            }
        }

        #pragma unroll
        for (int j = 0; j < 4; j++) {
            int node = base + n0 + j;
            if (node < n) {
                ushort4 v;
                v.x = f32_to_bf16_rne(acc[j][0]);
                v.y = f32_to_bf16_rne(acc[j][1]);
                v.z = f32_to_bf16_rne(acc[j][2]);
                v.w = f32_to_bf16_rne(acc[j][3]);
                *(ushort4*)&outb[(size_t)node * F + (half << 6) + f0] = v;
            }
        }
    }
}

// ---------------- Aggregate: wave-per-node, bf16 rows (256B), unroll 8 ----------------
// out[i] = relu(sum_{e: dst=i} norm*hl[src] + dinv_i^2*hl[i] + b)   (f32 out)

template <int POOL>
__global__ __launch_bounds__(256) void agg_kernel(const unsigned* __restrict__ hlb,   // bf16 rows
                                                  const int* __restrict__ offs,
                                                  const int2* __restrict__ csr,
                                                  const float* __restrict__ dinv,
                                                  const float* __restrict__ bias,
                                                  float* __restrict__ out,
                                                  const int* __restrict__ batch, int n) {
    const int lane = threadIdx.x & 63;
    const int i = blockIdx.x * 4 + (threadIdx.x >> 6);   // wave id == node id
    if (i >= n) return;

    // row pointer for this lane: hlb is [n][64] dwords (2 bf16 each)
    const unsigned* __restrict__ rowp = hlb + lane;

    float ax = 0.0f, ay = 0.0f;
    const int e0 = offs[i], e1 = offs[i + 1];
    int e = e0;
    for (; e + 8 <= e1; e += 8) {
        int2 c0 = csr[e + 0]; int2 c1 = csr[e + 1];
        int2 c2 = csr[e + 2]; int2 c3 = csr[e + 3];
        int2 c4 = csr[e + 4]; int2 c5 = csr[e + 5];
        int2 c6 = csr[e + 6]; int2 c7 = csr[e + 7];
        unsigned r0 = rowp[(size_t)c0.x << 6];
        unsigned r1 = rowp[(size_t)c1.x << 6];
        unsigned r2 = rowp[(size_t)c2.x << 6];
        unsigned r3 = rowp[(size_t)c3.x << 6];
        unsigned r4 = rowp[(size_t)c4.x << 6];
        unsigned r5 = rowp[(size_t)c5.x << 6];
        unsigned r6 = rowp[(size_t)c6.x << 6];
        unsigned r7 = rowp[(size_t)c7.x << 6];
        float2 f0 = bf2unpack(r0), f1 = bf2unpack(r1), f2 = bf2unpack(r2), f3 = bf2unpack(r3);
        float2 f4 = bf2unpack(r4), f5 = bf2unpack(r5), f6 = bf2unpack(r6), f7 = bf2unpack(r7);
        float n0 = __int_as_float(c0.y), n1 = __int_as_float(c1.y);
        float n2 = __int_as_float(c2.y), n3 = __int_as_float(c3.y);
        float n4 = __int_as_float(c4.y), n5 = __int_as_float(c5.y);
        float n6 = __int_as_float(c6.y), n7 = __int_as_float(c7.y);
        ax += f0.x * n0 + f1.x * n1 + f2.x * n2 + f3.x * n3
            + f4.x * n4 + f5.x * n5 + f6.x * n6 + f7.x * n7;
        ay += f0.y * n0 + f1.y * n1 + f2.y * n2 + f3.y * n3
            + f4.y * n4 + f5.y * n5 + f6.y * n6 + f7.y * n7;
    }
    for (; e < e1; e++) {
        int2 c = csr[e];
        float2 f = bf2unpack(rowp[(size_t)c.x << 6]);
        float nf = __int_as_float(c.y);
        ax += f.x * nf;
        ay += f.y * nf;
    }

    {   // self loop
        float di = dinv[i];
        float2 s = bf2unpack(rowp[(size_t)i << 6]);
        ax += s.x * di * di;
        ay += s.y * di * di;
    }

    float2 bv = ((const float2*)bias)[lane];
    float rx = fmaxf(ax + bv.x, 0.0f);
    float ry = fmaxf(ay + bv.y, 0.0f);

    if (POOL) {
        int g = batch[i];
        atomicMax((int*)&out[(size_t)g * F + 2 * lane + 0], __float_as_int(rx));
        atomicMax((int*)&out[(size_t)g * F + 2 * lane + 1], __float_as_int(ry));
    } else {
        ((float2*)out)[(size_t)i * 64 + lane] = make_float2(rx, ry);
    }
}

// ---------------- MLP head + log_softmax ----------------

__global__ __launch_bounds__(128) void mlp_kernel(const float* __restrict__ pooled,
                                                  const float* __restrict__ Wp1,
                                                  const float* __restrict__ bp1,
                                                  const float* __restrict__ Wp2,
                                                  const float* __restrict__ bp2,
                                                  float* __restrict__ out) {
    __shared__ float pl[F];
    __shared__ float s0[2], s1[2];
    int g = blockIdx.x, t = threadIdx.x;
    pl[t] = pooled[(size_t)g * F + t];
    __syncthreads();
    float a = bp1[t];
    #pragma unroll 8
    for (int k = 0; k < F; k++) a += pl[k] * Wp1[k * F + t];
    float p0 = a * Wp2[t * 2 + 0];
    float p1 = a * Wp2[t * 2 + 1];
    #pragma unroll
    for (int d = 32; d > 0; d >>= 1) {
        p0 += __shfl_down(p0, d, 64);
        p1 += __shfl_down(p1, d, 64);
    }
    if ((t & 63) == 0) { s0[t >> 6] = p0; s1[t >> 6] = p1; }
    __syncthreads();
    if (t == 0) {
        float l0 = s0[0] + s0[1] + bp2[0];
        float l1 = s1[0] + s1[1] + bp2[1];
        float m = fmaxf(l0, l1);
        float lse = m + logf(expf(l0 - m) + expf(l1 - m));
        out[g * 2 + 0] = l0 - lse;
        out[g * 2 + 1] = l1 - lse;
    }
}

// ---------------- launch ----------------

extern "C" void kernel_launch(void* const* d_in, const int* in_sizes, int n_in,
                              void* d_out, int out_size, void* d_ws, size_t ws_size,
                              hipStream_t stream) {
    const float* x    = (const float*)d_in[0];
    const int*   ei   = (const int*)d_in[1];
    const int*   batch= (const int*)d_in[2];
    const float* W1 = (const float*)d_in[3];  const float* b1 = (const float*)d_in[4];
    const float* W2 = (const float*)d_in[5];  const float* b2 = (const float*)d_in[6];
    const float* W3 = (const float*)d_in[7];  const float* b3 = (const float*)d_in[8];
    const float* Wp1= (const float*)d_in[9];  const float* bp1= (const float*)d_in[10];
    const float* Wp2= (const float*)d_in[11]; const float* bp2= (const float*)d_in[12];

    const int N = in_sizes[0] / F;
    const int E = in_sizes[1] / 2;
    const int G = out_size / 2;

    char* w = (char*)d_ws;
    size_t off = 0;
    auto alloc = [&](size_t bytes) -> void* {
        void* p = w + off;
        off = (off + bytes + 255) & ~(size_t)255;
        return p;
    };
    unsigned short* hlb = (unsigned short*)alloc((size_t)N * F * 2);  // bf16 GEMM out
    float* hbuf   = (float*)alloc((size_t)N * F * 4);                 // f32 agg out
    int*   deg    = (int*)alloc((size_t)N * 4);
    int*   cursor = (int*)alloc((size_t)N * 4);
    int*   offs   = (int*)alloc((size_t)(N + 1) * 4);
    float* dinv   = (float*)alloc((size_t)N * 4);
    int2*  csr    = (int2*)alloc((size_t)E * 8);
    float* pooled = (float*)alloc((size_t)G * F * 4);

    const int* srcp = ei;
    const int* dstp = ei + E;

    hipMemsetAsync(deg,    0, (size_t)N * 4, stream);
    hipMemsetAsync(cursor, 0, (size_t)N * 4, stream);
    hipMemsetAsync(pooled, 0, (size_t)G * F * 4, stream);

    const int eb = (E + 255) / 256;
    const int nb = (N + 255) / 256;
    count_kernel<<<eb, 256, 0, stream>>>(dstp, deg, E);
    dinv_kernel<<<nb, 256, 0, stream>>>(deg, dinv, N);
    scan_kernel<<<1, 1024, 0, stream>>>(deg, offs, N);
    fill_kernel<<<eb, 256, 0, stream>>>(srcp, dstp, offs, cursor, dinv, csr, E);

    const int ab = (N + 3) / 4;   // 4 waves (nodes) per block
    dim3 gg(512, 2);
    gemm_kernel<<<gg, 256, 0, stream>>>(x, W1, hlb, N);
    agg_kernel<0><<<ab, 256, 0, stream>>>((const unsigned*)hlb, offs, csr, dinv, b1, hbuf, nullptr, N);
    gemm_kernel<<<gg, 256, 0, stream>>>(hbuf, W2, hlb, N);
    agg_kernel<0><<<ab, 256, 0, stream>>>((const unsigned*)hlb, offs, csr, dinv, b2, hbuf, nullptr, N);
    gemm_kernel<<<gg, 256, 0, stream>>>(hbuf, W3, hlb, N);
    agg_kernel<1><<<ab, 256, 0, stream>>>((const unsigned*)hlb, offs, csr, dinv, b3, pooled, batch, N);
    mlp_kernel<<<G, 128, 0, stream>>>(pooled, Wp1, bp1, Wp2, bp2, (float*)d_out);
}